// Round 10
// baseline (170.303 us; speedup 1.0000x reference)
//
#include <hip/hip_runtime.h>
#include <hip/hip_bf16.h>

typedef __bf16 bf16x8 __attribute__((ext_vector_type(8)));
typedef float f32x4 __attribute__((ext_vector_type(4)));
typedef float f32x16 __attribute__((ext_vector_type(16)));
typedef int int4v __attribute__((ext_vector_type(4)));
typedef unsigned int uint4v __attribute__((ext_vector_type(4)));
typedef unsigned short u16x8 __attribute__((ext_vector_type(8)));

#define N_NODES 8192
#define D_FEAT 128

// Round-9 diagnosis: adjacency row stride (32 KiB) == 0 mod channel
// interleave span -> at chunk c the whole GPU reads channels {4c..4c+3}
// of ~128 (phase-locked by barrier-paced loops). Fix: per-block chunk
// phase rotation cc = (c + bx&31) & 31 spreads concurrent blocks over
// all 32 chunk-phases = all channels. Everything else = round-6 best.

// ---------------------------------------------------------------------------
__device__ __forceinline__ bf16x8 unpack_byte(unsigned dword, int sh) {
  unsigned P = ((dword >> sh) & 0xFFu) * 0x8001u;
  uint4v c;
  c[0] = (P & 0x10001u) * 0x3F80u;
  c[1] = ((P >> 2) & 0x10001u) * 0x3F80u;
  c[2] = ((P >> 4) & 0x10001u) * 0x3F80u;
  c[3] = ((P >> 6) & 0x10001u) * 0x3F80u;
  return __builtin_bit_cast(bf16x8, c);
}

// ---------------------------------------------------------------------------
// Bpk fragment build (verified rounds 2-6). Fragment f = kk*256 + ng*64 + l
// holds, at element e: F[sigma(kk*16 + (l>>5)*8 + e)][ng*32 + (l&31)],
// sigma(p) = 256*(p>>8) + 32*((p>>3)&7) + 4*(p&7) + ((p>>6)&3)
__device__ __forceinline__ void bpk32_store(const float* __restrict__ src,
                                            unsigned short* __restrict__ Bpk,
                                            int W) {
  const int kk = W >> 8;
  const int ng = (W >> 6) & 3;
  const int l = W & 63;
  const int d = ng * 32 + (l & 31);
  const int p0 = kk * 16 + (l >> 5) * 8;
  const int n0 = (p0 >> 8) * 256 + ((p0 >> 3) & 7) * 32 + ((p0 >> 6) & 3);
  u16x8 pk;
#pragma unroll
  for (int e = 0; e < 8; ++e) {
    __bf16 v = (__bf16)src[(long)(n0 + 4 * e) * D_FEAT + d];
    pk[e] = __builtin_bit_cast(unsigned short, v);
  }
  *(u16x8*)(Bpk + (long)W * 8) = pk;
}

__global__ __launch_bounds__(256) void bpk_build32_kernel(
    const float* __restrict__ src, unsigned short* __restrict__ Bpk) {
  bpk32_store(src, Bpk, blockIdx.x * 256 + threadIdx.x);
}

// ---------------------------------------------------------------------------
// Fused pack+GEMM layer (round-6 geometry + chunk-phase rotation).
// Block = 32 rows x 128 cols, 512 thr = 8 waves = 4 ng x 2 kh2;
// 32 chunks of 256 ints, processed in rotated order PC(c).
__global__ __launch_bounds__(512, 2) void fused_layer_kernel(
    const int* __restrict__ adj, const unsigned short* __restrict__ Bpk,
    const float* __restrict__ fin, float* __restrict__ fout) {
  __shared__ unsigned bitsL[2][320];              // [buf][row*10 + slot]
  __shared__ int degL[32];
  __shared__ __align__(16) f32x4 red[4][4][64];   // 16 KiB split-K combine

  const int tid = threadIdx.x;
  const int lane = tid & 63;
  const int w = tid >> 6;       // 0..7
  const int ng = w & 3;         // 32-col group
  const int kh2 = w >> 2;       // K-half of each chunk
  const int l31 = lane & 31;
  const int lh = lane >> 5;
  const int lh8 = lh * 8;
  const int m0 = blockIdx.x * 32;
  const int phase = blockIdx.x & 31;   // chunk-phase rotation

#define PC(C) ((phase + (C)) & 31)

  const int4v* aB0 = (const int4v*)(adj + ((long)(m0 + w) << 13)) + lane;
  const int4v* aB1 = (const int4v*)(adj + ((long)(m0 + 8 + w) << 13)) + lane;
  const int4v* aB2 = (const int4v*)(adj + ((long)(m0 + 16 + w) << 13)) + lane;
  const int4v* aB3 = (const int4v*)(adj + ((long)(m0 + 24 + w) << 13)) + lane;

  int cnt0 = 0, cnt1 = 0, cnt2 = 0, cnt3 = 0;

#define DO_BALLOT(R0, R1, R2, R3, BUF)                                       \
  {                                                                          \
    const int e_ = lane >> 1;                                                \
    _Pragma("unroll") for (int i = 0; i < 4; ++i) {                          \
      int4v vv = (i == 0) ? (R0) : (i == 1) ? (R1) : (i == 2) ? (R2) : (R3); \
      unsigned long long b0 = __ballot(vv[0] != 0);                          \
      unsigned long long b1 = __ballot(vv[1] != 0);                          \
      unsigned long long b2 = __ballot(vv[2] != 0);                          \
      unsigned long long b3 = __ballot(vv[3] != 0);                          \
      int pc = __popcll(b0) + __popcll(b1) + __popcll(b2) + __popcll(b3);    \
      if (i == 0) cnt0 += pc;                                                \
      if (i == 1) cnt1 += pc;                                                \
      if (i == 2) cnt2 += pc;                                                \
      if (i == 3) cnt3 += pc;                                                \
      unsigned long long bsel = b0;                                          \
      if (e_ == 1) bsel = b1;                                                \
      if (e_ == 2) bsel = b2;                                                \
      if (e_ == 3) bsel = b3;                                                \
      unsigned dv = (lane & 1) ? (unsigned)(bsel >> 32) : (unsigned)bsel;    \
      if (lane < 8) bitsL[BUF][(i * 8 + w) * 10 + lane] = dv;                \
    }                                                                        \
  }

  f32x16 acc = {0.f, 0.f, 0.f, 0.f, 0.f, 0.f, 0.f, 0.f,
                0.f, 0.f, 0.f, 0.f, 0.f, 0.f, 0.f, 0.f};

  // GEMM one chunk; CP is the PHYSICAL chunk index (Bpk kk base).
#define DO_GEMM(CP, BUF)                                                     \
  {                                                                          \
    const bf16x8* bp = (const bf16x8*)Bpk +                                  \
                       (((long)((CP)*16 + kh2 * 8)) << 8) + ng * 64 + lane;  \
    bf16x8 bv0 = bp[0], bv1 = bp[256], bv2 = bp[512], bv3 = bp[768];         \
    bf16x8 bv4 = bp[1024], bv5 = bp[1280], bv6 = bp[1536], bv7 = bp[1792];   \
    const unsigned* bl = &bitsL[BUF][l31 * 10 + kh2 * 4];                    \
    unsigned q0 = bl[0], q1 = bl[1], q2 = bl[2], q3 = bl[3];                 \
    acc = __builtin_amdgcn_mfma_f32_32x32x16_bf16(unpack_byte(q0, lh8),      \
                                                  bv0, acc, 0, 0, 0);        \
    acc = __builtin_amdgcn_mfma_f32_32x32x16_bf16(unpack_byte(q0, lh8 + 16), \
                                                  bv1, acc, 0, 0, 0);        \
    acc = __builtin_amdgcn_mfma_f32_32x32x16_bf16(unpack_byte(q1, lh8),      \
                                                  bv2, acc, 0, 0, 0);        \
    acc = __builtin_amdgcn_mfma_f32_32x32x16_bf16(unpack_byte(q1, lh8 + 16), \
                                                  bv3, acc, 0, 0, 0);        \
    acc = __builtin_amdgcn_mfma_f32_32x32x16_bf16(unpack_byte(q2, lh8),      \
                                                  bv4, acc, 0, 0, 0);        \
    acc = __builtin_amdgcn_mfma_f32_32x32x16_bf16(unpack_byte(q2, lh8 + 16), \
                                                  bv5, acc, 0, 0, 0);        \
    acc = __builtin_amdgcn_mfma_f32_32x32x16_bf16(unpack_byte(q3, lh8),      \
                                                  bv6, acc, 0, 0, 0);        \
    acc = __builtin_amdgcn_mfma_f32_32x32x16_bf16(unpack_byte(q3, lh8 + 16), \
                                                  bv7, acc, 0, 0, 0);        \
  }

  // Prologue: physical chunks PC(0) -> avA, PC(1) -> avB; ballot PC(0)->buf0.
  int4v avA0 = aB0[PC(0) * 64], avA1 = aB1[PC(0) * 64];
  int4v avA2 = aB2[PC(0) * 64], avA3 = aB3[PC(0) * 64];
  int4v avB0 = aB0[PC(1) * 64], avB1 = aB1[PC(1) * 64];
  int4v avB2 = aB2[PC(1) * 64], avB3 = aB3[PC(1) * 64];
  DO_BALLOT(avA0, avA1, avA2, avA3, 0)
  __syncthreads();

  // BODY(c): prefetch PC(c+2) into CUR; ballot logical c+1 (OTH) -> buf
  // (c+1)&1; GEMM logical c (physical PC(c)) from buf c&1; barrier.
#define BODY(C, CUR0, CUR1, CUR2, CUR3, OTH0, OTH1, OTH2, OTH3)              \
  {                                                                          \
    if ((C) + 2 < 32) {                                                      \
      CUR0 = aB0[PC((C) + 2) * 64];                                          \
      CUR1 = aB1[PC((C) + 2) * 64];                                          \
      CUR2 = aB2[PC((C) + 2) * 64];                                          \
      CUR3 = aB3[PC((C) + 2) * 64];                                          \
    }                                                                        \
    if ((C) + 1 < 32) DO_BALLOT(OTH0, OTH1, OTH2, OTH3, ((C) + 1) & 1)       \
    DO_GEMM(PC(C), (C)&1)                                                    \
    __syncthreads();                                                         \
  }

  for (int c = 0; c < 32; c += 2) {
    BODY(c, avA0, avA1, avA2, avA3, avB0, avB1, avB2, avB3)
    BODY(c + 1, avB0, avB1, avB2, avB3, avA0, avA1, avA2, avA3)
  }
#undef BODY
#undef DO_GEMM
#undef DO_BALLOT
#undef PC

  if (lane == 0) {
    degL[w] = cnt0;
    degL[8 + w] = cnt1;
    degL[16 + w] = cnt2;
    degL[24 + w] = cnt3;
  }

  // Split-K2 combine: kh2=1 waves store, kh2=0 waves add.
  if (kh2) {
#define ST4(c)                                                               \
  red[ng][c][lane] = __builtin_shufflevector(acc, acc, 4 * (c), 4 * (c) + 1, \
                                             4 * (c) + 2, 4 * (c) + 3);
    ST4(0) ST4(1) ST4(2) ST4(3)
#undef ST4
  }
  __syncthreads();
  if (kh2) return;
#pragma unroll
  for (int c = 0; c < 4; ++c) {
    f32x4 r = red[ng][c][lane];
#pragma unroll
    for (int k = 0; k < 4; ++k) acc[4 * c + k] += r[k];
  }

  // Epilogue (verified m101 C/D layout): col = ng*32+l31,
  // row32 = (r&3) + 8*(r>>2) + 4*lh.
#pragma unroll
  for (int r = 0; r < 16; ++r) {
    const int row32 = (r & 3) + 8 * (r >> 2) + 4 * lh;
    const int row = m0 + row32;
    const int dg = degL[row32];
    const long off = (long)row * D_FEAT + ng * 32 + l31;
    fout[off] = dg > 0 ? acc[r] * (1.0f / (float)dg) : fin[off];
  }
}

// ---------------------------------------------------------------------------
// Fallback path (round-1 verified), used only if ws too small.
__global__ __launch_bounds__(256) void transpose_cast_kernel(
    const float* __restrict__ src, unsigned short* __restrict__ dst) {
  __shared__ float tile[64][129];
  const int t = threadIdx.x;
  const int nbase = blockIdx.x * 64;
#pragma unroll
  for (int i = 0; i < 32; ++i) {
    int idx = t + i * 256;
    int nl = idx >> 7;
    int d = idx & 127;
    tile[nl][d] = src[(long)(nbase + nl) * D_FEAT + d];
  }
  __syncthreads();
#pragma unroll
  for (int i = 0; i < 32; ++i) {
    int idx = t + i * 256;
    int d = idx >> 6;
    int nl = idx & 63;
    __bf16 b = (__bf16)tile[nl][d];
    dst[(long)d * N_NODES + nbase + nl] = __builtin_bit_cast(unsigned short, b);
  }
}

__global__ __launch_bounds__(512) void layer_kernel_direct(
    const int* __restrict__ adj, const unsigned short* __restrict__ BT,
    const float* __restrict__ fin, float* __restrict__ fout) {
  const int tid = threadIdx.x;
  const int lane = tid & 63;
  const int w = tid >> 6;
  const int m0 = blockIdx.x * 32 + (w >> 2) * 16;
  const int n0 = (w & 3) * 32;
  const int lr = lane & 15;
  const int kc = lane >> 4;

  const int4v* ap = (const int4v*)(adj + (long)(m0 + lr) * N_NODES + kc * 8);
  const bf16x8* bp0 = (const bf16x8*)(BT + (long)(n0 + lr) * N_NODES + kc * 8);
  const bf16x8* bp1 =
      (const bf16x8*)(BT + (long)(n0 + 16 + lr) * N_NODES + kc * 8);

  f32x4 acc0 = {0.f, 0.f, 0.f, 0.f};
  f32x4 acc1 = {0.f, 0.f, 0.f, 0.f};
  int degv = 0;

#pragma unroll 4
  for (int k = 0; k < N_NODES; k += 32) {
    int4v alo = ap[0];
    int4v ahi = ap[1];
    bf16x8 b0 = bp0[0];
    bf16x8 b1 = bp1[0];
    ap += 8;
    bp0 += 4;
    bp1 += 4;
    unsigned short u[8];
    u[0] = alo[0] ? 0x3F80 : 0;
    u[1] = alo[1] ? 0x3F80 : 0;
    u[2] = alo[2] ? 0x3F80 : 0;
    u[3] = alo[3] ? 0x3F80 : 0;
    u[4] = ahi[0] ? 0x3F80 : 0;
    u[5] = ahi[1] ? 0x3F80 : 0;
    u[6] = ahi[2] ? 0x3F80 : 0;
    u[7] = ahi[3] ? 0x3F80 : 0;
    degv += alo[0] + alo[1] + alo[2] + alo[3] + ahi[0] + ahi[1] + ahi[2] +
            ahi[3];
    bf16x8 a;
    memcpy(&a, u, 16);
    acc0 = __builtin_amdgcn_mfma_f32_16x16x32_bf16(a, b0, acc0, 0, 0, 0);
    acc1 = __builtin_amdgcn_mfma_f32_16x16x32_bf16(a, b1, acc1, 0, 0, 0);
  }

  degv += __shfl_xor(degv, 16);
  degv += __shfl_xor(degv, 32);
  int dgv[4];
#pragma unroll
  for (int j = 0; j < 4; ++j) dgv[j] = __shfl(degv, kc * 4 + j);

#pragma unroll
  for (int t = 0; t < 2; ++t) {
    const f32x4 acc = t ? acc1 : acc0;
    const int col = n0 + t * 16 + lr;
#pragma unroll
    for (int j = 0; j < 4; ++j) {
      const long off = (long)(m0 + kc * 4 + j) * D_FEAT + col;
      fout[off] = dgv[j] > 0 ? acc[j] * (1.0f / (float)dgv[j]) : fin[off];
    }
  }
}

// ---------------------------------------------------------------------------
extern "C" void kernel_launch(void* const* d_in, const int* in_sizes, int n_in,
                              void* d_out, int out_size, void* d_ws,
                              size_t ws_size, hipStream_t stream) {
  const float* features = (const float*)d_in[0];
  const int* adj = (const int*)d_in[1];
  float* out = (float*)d_out;
  const long NN = (long)N_NODES * N_NODES;

  const size_t BPK_BYTES = (size_t)D_FEAT * N_NODES * 2;  // 2 MiB
  const size_t NEED = BPK_BYTES + 256;

  if (ws_size >= NEED) {
    unsigned short* Bpk = (unsigned short*)d_ws;

    // Layer 1
    bpk_build32_kernel<<<512, 256, 0, stream>>>(features, Bpk);
    fused_layer_kernel<<<256, 512, 0, stream>>>(adj, Bpk, features, out);
    // Layer 2
    bpk_build32_kernel<<<512, 256, 0, stream>>>(out, Bpk);
    fused_layer_kernel<<<256, 512, 0, stream>>>(adj + NN, Bpk, out, out);
  } else {
    // Fallback: round-1 verified path (needs only 2 MiB ws)
    unsigned short* BTw = (unsigned short*)d_ws;
    transpose_cast_kernel<<<N_NODES / 64, 256, 0, stream>>>(features, BTw);
    layer_kernel_direct<<<N_NODES / 32, 512, 0, stream>>>(adj, BTw, features,
                                                          out);
    transpose_cast_kernel<<<N_NODES / 64, 256, 0, stream>>>(out, BTw);
    layer_kernel_direct<<<N_NODES / 32, 512, 0, stream>>>(adj + NN, BTw, out,
                                                          out);
  }
}